// Round 1
// baseline (92.210 us; speedup 1.0000x reference)
//
#include <hip/hip_runtime.h>
#include <math.h>

// Problem constants
#define BB 8
#define KK 256
#define DD 256
// flattened batch stride
#define BS 65536  // 256*256

// ---------------------------------------------------------------------------
// K1: projections.
//   L[b][i][d]  = sum_f x[b][f][i] * W[d][f]       + b_lin[d]   (row-major [i][d])
//   Rt[b][d][j] = sum_f x[b][f][j] * W[d][256+f]                (d-major   [d][j])
//   c12[d] = 0.6*a[d], c12[256+d] = 0.4*a[d]
// grid (32 d-tiles, 8 b), block 256 (lane = n). d-tile = 8.
// W reads are block-uniform -> expect s_load; x reads coalesced over n.
// ---------------------------------------------------------------------------
__global__ __launch_bounds__(256, 2) void k1_proj(
    const float* __restrict__ x, const float* __restrict__ W,
    const float* __restrict__ b_lin, const float* __restrict__ a,
    float* __restrict__ L, float* __restrict__ Rt, float* __restrict__ c12) {
  const int n = threadIdx.x;
  const int b = blockIdx.y;
  const int d0 = blockIdx.x * 8;
  const float* xb = x + ((size_t)b << 16);

  float al[8], ar[8];
#pragma unroll
  for (int i = 0; i < 8; ++i) { al[i] = 0.f; ar[i] = 0.f; }

#pragma unroll 4
  for (int f = 0; f < 256; ++f) {
    float xv = xb[f * 256 + n];
#pragma unroll
    for (int di = 0; di < 8; ++di) {
      al[di] = fmaf(W[(d0 + di) * 512 + f], xv, al[di]);
      ar[di] = fmaf(W[(d0 + di) * 512 + 256 + f], xv, ar[di]);
    }
  }

  // epilogue: fold b_lin into L, write L row-major (per-thread contiguous 8)
  float lv[8];
#pragma unroll
  for (int di = 0; di < 8; ++di) lv[di] = al[di] + b_lin[d0 + di];
  float* Lrow = L + ((size_t)b << 16) + n * 256 + d0;
  *(float4*)(Lrow + 0) = make_float4(lv[0], lv[1], lv[2], lv[3]);
  *(float4*)(Lrow + 4) = make_float4(lv[4], lv[5], lv[6], lv[7]);
  // Rt coalesced over n
#pragma unroll
  for (int di = 0; di < 8; ++di) Rt[((size_t)b << 16) + (d0 + di) * 256 + n] = ar[di];

  if (blockIdx.x == 0 && b == 0) {
    c12[n] = 0.6f * a[n];
    c12[256 + n] = 0.4f * a[n];
  }
}

// ---------------------------------------------------------------------------
// K2: e scores + bias + mask + row softmax; writes attn TRANSPOSED At[b][j][i].
// grid (64 i-tiles, 8 b) = 512 blocks (2 blocks/CU), block 256 (lane = j).
// i-tile = 4. Inner loop over d: Rt coalesced vector load; L rows and c1/c2
// are block-uniform -> s_load. 3 VALU/(i,d): add + 2 fma (|t| is a modifier).
// ---------------------------------------------------------------------------
__global__ __launch_bounds__(256, 2) void k2_scores(
    const float* __restrict__ Rt, const float* __restrict__ L,
    const float* __restrict__ c12, const int* __restrict__ adj,
    const float* __restrict__ bias, float* __restrict__ At) {
  const int j = threadIdx.x;
  const int b = blockIdx.y;
  const int i0 = blockIdx.x * 4;

  const float* Lb = L + ((size_t)b << 16) + i0 * 256;  // 4 rows of 256
  const float* Rb = Rt + ((size_t)b << 16);

  float e0 = 0.f, e1 = 0.f, e2 = 0.f, e3 = 0.f;
#pragma unroll 4
  for (int d = 0; d < 256; ++d) {
    float rv = Rb[d * 256 + j];
    float cc1 = c12[d];
    float cc2 = c12[256 + d];
    float t0 = Lb[d] + rv;
    float t1 = Lb[256 + d] + rv;
    float t2 = Lb[512 + d] + rv;
    float t3 = Lb[768 + d] + rv;
    e0 = fmaf(cc2, fabsf(t0), fmaf(cc1, t0, e0));
    e1 = fmaf(cc2, fabsf(t1), fmaf(cc1, t1, e1));
    e2 = fmaf(cc2, fabsf(t2), fmaf(cc1, t2, e2));
    e3 = fmaf(cc2, fabsf(t3), fmaf(cc1, t3, e3));
  }

  float ev[4] = {e0, e1, e2, e3};
  const float NEG_INF = -__builtin_inff();
#pragma unroll
  for (int ii = 0; ii < 4; ++ii) {
    ev[ii] += bias[(i0 + ii) * 256 + j];
    int ad = adj[((size_t)b << 16) + (i0 + ii) * 256 + j];
    ev[ii] = (ad == 0) ? NEG_INF : ev[ii];
  }

  // row softmax over j (256 threads = 4 waves)
  __shared__ float red_max[4][4];  // [wave][ii]
  __shared__ float red_sum[4][4];
  const int wid = threadIdx.x >> 6;
  const int lane = threadIdx.x & 63;

#pragma unroll
  for (int ii = 0; ii < 4; ++ii) {
    float v = ev[ii];
#pragma unroll
    for (int off = 32; off >= 1; off >>= 1) v = fmaxf(v, __shfl_xor(v, off, 64));
    if (lane == 0) red_max[wid][ii] = v;
  }
  __syncthreads();
  float m[4], p[4];
#pragma unroll
  for (int ii = 0; ii < 4; ++ii) {
    m[ii] = fmaxf(fmaxf(red_max[0][ii], red_max[1][ii]),
                  fmaxf(red_max[2][ii], red_max[3][ii]));
    // all-masked row: reference sets e row to 0 -> uniform softmax. p=1 for all.
    p[ii] = (m[ii] == NEG_INF) ? 1.0f : expf(ev[ii] - m[ii]);
  }
#pragma unroll
  for (int ii = 0; ii < 4; ++ii) {
    float v = p[ii];
#pragma unroll
    for (int off = 32; off >= 1; off >>= 1) v += __shfl_xor(v, off, 64);
    if (lane == 0) red_sum[wid][ii] = v;
  }
  __syncthreads();
  float4 o;
  {
    float s0 = red_sum[0][0] + red_sum[1][0] + red_sum[2][0] + red_sum[3][0];
    float s1 = red_sum[0][1] + red_sum[1][1] + red_sum[2][1] + red_sum[3][1];
    float s2 = red_sum[0][2] + red_sum[1][2] + red_sum[2][2] + red_sum[3][2];
    float s3 = red_sum[0][3] + red_sum[1][3] + red_sum[2][3] + red_sum[3][3];
    o = make_float4(p[0] / s0, p[1] / s1, p[2] / s2, p[3] / s3);
  }
  // attn transposed: At[b][j][i0..i0+3]
  *(float4*)(At + ((size_t)b << 16) + j * 256 + i0) = o;
}

// ---------------------------------------------------------------------------
// K3: Y[b][f][n] = sigmoid( sum_j x[b][f][j] * At[b][j][n] ) + x[b][f][n]
// grid (32 f-tiles, 8 b), block 256 (lane = n). f-tile = 8.
// At loads coalesced over n; x rows block-uniform -> s_load.
// ---------------------------------------------------------------------------
__global__ __launch_bounds__(256, 2) void k3_out(
    const float* __restrict__ x, const float* __restrict__ At,
    float* __restrict__ out) {
  const int n = threadIdx.x;
  const int b = blockIdx.y;
  const int f0 = blockIdx.x * 8;
  const float* xb = x + ((size_t)b << 16);
  const float* Ab = At + ((size_t)b << 16);

  float acc[8];
#pragma unroll
  for (int i = 0; i < 8; ++i) acc[i] = 0.f;

#pragma unroll 4
  for (int jj = 0; jj < 256; ++jj) {
    float av = Ab[jj * 256 + n];
#pragma unroll
    for (int fi = 0; fi < 8; ++fi)
      acc[fi] = fmaf(xb[(f0 + fi) * 256 + jj], av, acc[fi]);
  }

#pragma unroll
  for (int fi = 0; fi < 8; ++fi) {
    float s = 1.0f / (1.0f + expf(-acc[fi]));
    out[((size_t)b << 16) + (f0 + fi) * 256 + n] = s + xb[(f0 + fi) * 256 + n];
  }
}

extern "C" void kernel_launch(void* const* d_in, const int* in_sizes, int n_in,
                              void* d_out, int out_size, void* d_ws, size_t ws_size,
                              hipStream_t stream) {
  const float* x = (const float*)d_in[0];
  const int* adj = (const int*)d_in[1];
  const float* W = (const float*)d_in[2];
  const float* b_lin = (const float*)d_in[3];
  const float* a = (const float*)d_in[4];
  const float* bias = (const float*)d_in[5];
  float* out = (float*)d_out;

  float* L = (float*)d_ws;            // B*K*D
  float* Rt = L + BB * BS;            // B*K*D
  float* At = Rt + BB * BS;           // B*K*K
  float* c12 = At + BB * BS;          // 512

  k1_proj<<<dim3(32, BB), 256, 0, stream>>>(x, W, b_lin, a, L, Rt, c12);
  k2_scores<<<dim3(64, BB), 256, 0, stream>>>(Rt, L, c12, adj, bias, At);
  k3_out<<<dim3(32, BB), 256, 0, stream>>>(x, At, out);
}

// Round 2
// 66.267 us; speedup vs baseline: 1.3915x; 1.3915x over previous
//
#include <hip/hip_runtime.h>
#include <math.h>

// Problem constants
#define BB 8
#define KK 256
#define DD 256
#define BS 65536  // 256*256 batch stride

// ---------------------------------------------------------------------------
// K1: projections, pre-scaled for the k2 inner loop.
//   raw L[i,d] = sum_f x[b][f][i] * W[d][f]        (left)
//   raw R[j,d] = sum_f x[b][f][j] * W[d][256+f]    (right)
// Outputs:
//   L2p[b][i][d] = |0.4*a[d]| * (L[i,d] + b_lin[d])   row-major [i][d]
//   R2t[b][d][j] = |0.4*a[d]| * R[j,d]                transposed [d][j]
//   SR[b][j]    += sum_d 0.6*a[d]*R[j,d]              (atomicAdd partials)
//   s[d]         = sign(a[d])                         (written by block 0)
// NOTE: the left separable term SL[i] = sum_d 0.6*a[d]*(L[i,d]+b_lin[d]) is a
// per-row constant in e[i,:] -> cancels in softmax -> dropped entirely.
// grid (64 d-tiles, 8 b) = 512 blocks (2/CU, 8 waves/CU), block 256 (lane=n).
// d-tile = 4 -> 8 independent FMA chains/thread.
// ---------------------------------------------------------------------------
__global__ __launch_bounds__(256, 2) void k1_proj(
    const float* __restrict__ x, const float* __restrict__ W,
    const float* __restrict__ b_lin, const float* __restrict__ a,
    float* __restrict__ L2p, float* __restrict__ R2t,
    float* __restrict__ SR, float* __restrict__ s) {
  const int n = threadIdx.x;
  const int b = blockIdx.y;
  const int d0 = blockIdx.x * 4;
  const float* xb = x + ((size_t)b << 16);

  float al[4], ar[4];
#pragma unroll
  for (int i = 0; i < 4; ++i) { al[i] = 0.f; ar[i] = 0.f; }

#pragma unroll 8
  for (int f = 0; f < 256; ++f) {
    float xv = xb[f * 256 + n];
#pragma unroll
    for (int di = 0; di < 4; ++di) {
      al[di] = fmaf(W[(d0 + di) * 512 + f], xv, al[di]);
      ar[di] = fmaf(W[(d0 + di) * 512 + 256 + f], xv, ar[di]);
    }
  }

  float lv[4];
  float srp = 0.f;
#pragma unroll
  for (int di = 0; di < 4; ++di) {
    float av = a[d0 + di];
    float c2m = fabsf(0.4f * av);
    lv[di] = c2m * (al[di] + b_lin[d0 + di]);
    R2t[((size_t)b << 16) + (d0 + di) * 256 + n] = c2m * ar[di];
    srp = fmaf(0.6f * av, ar[di], srp);
  }
  *(float4*)(L2p + ((size_t)b << 16) + n * 256 + d0) =
      make_float4(lv[0], lv[1], lv[2], lv[3]);
  atomicAdd(&SR[b * 256 + n], srp);

  if (blockIdx.x == 0 && b == 0) s[n] = (a[n] >= 0.f) ? 1.f : -1.f;
}

// ---------------------------------------------------------------------------
// K2: e'[i,j] = SR[j] + bias[i,j] + sum_d s[d]*|L2p[i,d] + R2t[d,j]|
//     (+ mask, row softmax) -> writes attn TRANSPOSED At[b][j][i].
// grid (64 i-tiles, 8 b) = 512 blocks (2/CU), block 256 (lane = j). i-tile 4.
// Inner loop: 1 coalesced R load + 4 add + 4 fma (|t| = VOP3 modifier,
// s[d]/L2row/bias uniform -> scalar loads). 2 VALU per (i,j,d).
// ---------------------------------------------------------------------------
__global__ __launch_bounds__(256, 2) void k2_scores(
    const float* __restrict__ R2t, const float* __restrict__ L2p,
    const float* __restrict__ s, const float* __restrict__ SR,
    const int* __restrict__ adj, const float* __restrict__ bias,
    float* __restrict__ At) {
  const int j = threadIdx.x;
  const int b = blockIdx.y;
  const int i0 = blockIdx.x * 4;

  const float* Lb = L2p + ((size_t)b << 16) + i0 * 256;  // 4 uniform rows
  const float* Rb = R2t + ((size_t)b << 16);

  float e0 = 0.f, e1 = 0.f, e2 = 0.f, e3 = 0.f;
#pragma unroll 8
  for (int d = 0; d < 256; ++d) {
    float rv = Rb[d * 256 + j];
    float sd = s[d];
    float t0 = Lb[d] + rv;
    float t1 = Lb[256 + d] + rv;
    float t2 = Lb[512 + d] + rv;
    float t3 = Lb[768 + d] + rv;
    e0 = fmaf(sd, fabsf(t0), e0);
    e1 = fmaf(sd, fabsf(t1), e1);
    e2 = fmaf(sd, fabsf(t2), e2);
    e3 = fmaf(sd, fabsf(t3), e3);
  }

  const float srj = SR[b * 256 + j];
  float ev[4] = {e0, e1, e2, e3};
  const float NEG_INF = -__builtin_inff();
#pragma unroll
  for (int ii = 0; ii < 4; ++ii) {
    ev[ii] += srj + bias[(i0 + ii) * 256 + j];
    int ad = adj[((size_t)b << 16) + (i0 + ii) * 256 + j];
    ev[ii] = (ad == 0) ? NEG_INF : ev[ii];
  }

  // row softmax over j (256 threads = 4 waves)
  __shared__ float red_max[4][4];
  __shared__ float red_sum[4][4];
  const int wid = threadIdx.x >> 6;
  const int lane = threadIdx.x & 63;

#pragma unroll
  for (int ii = 0; ii < 4; ++ii) {
    float v = ev[ii];
#pragma unroll
    for (int off = 32; off >= 1; off >>= 1) v = fmaxf(v, __shfl_xor(v, off, 64));
    if (lane == 0) red_max[wid][ii] = v;
  }
  __syncthreads();
  float m[4], p[4];
#pragma unroll
  for (int ii = 0; ii < 4; ++ii) {
    m[ii] = fmaxf(fmaxf(red_max[0][ii], red_max[1][ii]),
                  fmaxf(red_max[2][ii], red_max[3][ii]));
    p[ii] = (m[ii] == NEG_INF) ? 1.0f : expf(ev[ii] - m[ii]);
  }
#pragma unroll
  for (int ii = 0; ii < 4; ++ii) {
    float v = p[ii];
#pragma unroll
    for (int off = 32; off >= 1; off >>= 1) v += __shfl_xor(v, off, 64);
    if (lane == 0) red_sum[wid][ii] = v;
  }
  __syncthreads();
  float4 o;
  {
    float s0 = red_sum[0][0] + red_sum[1][0] + red_sum[2][0] + red_sum[3][0];
    float s1 = red_sum[0][1] + red_sum[1][1] + red_sum[2][1] + red_sum[3][1];
    float s2 = red_sum[0][2] + red_sum[1][2] + red_sum[2][2] + red_sum[3][2];
    float s3 = red_sum[0][3] + red_sum[1][3] + red_sum[2][3] + red_sum[3][3];
    o = make_float4(p[0] / s0, p[1] / s1, p[2] / s2, p[3] / s3);
  }
  *(float4*)(At + ((size_t)b << 16) + j * 256 + i0) = o;
}

// ---------------------------------------------------------------------------
// K3: out[b][f][n] = sigmoid( sum_j x[b][f][j] * At[b][j][n] ) + x[b][f][n]
// grid (64 f-tiles, 8 b) = 512 blocks (2/CU), block 256 (lane = n). f-tile 4.
// At coalesced over n; x rows block-uniform -> scalar loads.
// ---------------------------------------------------------------------------
__global__ __launch_bounds__(256, 2) void k3_out(
    const float* __restrict__ x, const float* __restrict__ At,
    float* __restrict__ out) {
  const int n = threadIdx.x;
  const int b = blockIdx.y;
  const int f0 = blockIdx.x * 4;
  const float* xb = x + ((size_t)b << 16);
  const float* Ab = At + ((size_t)b << 16);

  float acc[4];
#pragma unroll
  for (int i = 0; i < 4; ++i) acc[i] = 0.f;

#pragma unroll 8
  for (int jj = 0; jj < 256; ++jj) {
    float av = Ab[jj * 256 + n];
#pragma unroll
    for (int fi = 0; fi < 4; ++fi)
      acc[fi] = fmaf(xb[(f0 + fi) * 256 + jj], av, acc[fi]);
  }

#pragma unroll
  for (int fi = 0; fi < 4; ++fi) {
    float sg = 1.0f / (1.0f + expf(-acc[fi]));
    out[((size_t)b << 16) + (f0 + fi) * 256 + n] = sg + xb[(f0 + fi) * 256 + n];
  }
}

extern "C" void kernel_launch(void* const* d_in, const int* in_sizes, int n_in,
                              void* d_out, int out_size, void* d_ws, size_t ws_size,
                              hipStream_t stream) {
  const float* x = (const float*)d_in[0];
  const int* adj = (const int*)d_in[1];
  const float* W = (const float*)d_in[2];
  const float* b_lin = (const float*)d_in[3];
  const float* a = (const float*)d_in[4];
  const float* bias = (const float*)d_in[5];
  float* out = (float*)d_out;

  float* L2p = (float*)d_ws;          // B*K*D
  float* R2t = L2p + BB * BS;         // B*K*D
  float* At = R2t + BB * BS;          // B*K*K
  float* SR = At + BB * BS;           // B*K
  float* s = SR + BB * KK;            // D

  hipMemsetAsync(SR, 0, BB * KK * sizeof(float), stream);
  k1_proj<<<dim3(64, BB), 256, 0, stream>>>(x, W, b_lin, a, L2p, R2t, SR, s);
  k2_scores<<<dim3(64, BB), 256, 0, stream>>>(R2t, L2p, s, SR, adj, bias, At);
  k3_out<<<dim3(64, BB), 256, 0, stream>>>(x, At, out);
}

// Round 3
// 50.619 us; speedup vs baseline: 1.8217x; 1.3091x over previous
//
#include <hip/hip_runtime.h>
#include <hip/hip_bf16.h>
#include <math.h>

#define BB 8
#define BS 65536  // 256*256

typedef __attribute__((ext_vector_type(8))) short short8v;
typedef __attribute__((ext_vector_type(4))) float f32x4;
typedef unsigned short u16;
typedef unsigned int u32;
typedef __attribute__((address_space(1))) const void gv_t;
typedef __attribute__((address_space(3))) void lv_t;

__device__ __forceinline__ u16 f2bf(float v) {
  __hip_bfloat16 h = __float2bfloat16(v);
  return *reinterpret_cast<u16*>(&h);
}

// ---------------------------------------------------------------------------
// prep_x: xh[b][f][n] = bf16(x)  (native, k3 A-operand)
//         xt[b][n][f] = bf16(x^T) (LDS-tiled transpose, k1 operands)
// grid (4 f-tiles, 4 n-tiles, 8 b), block 256.
// ---------------------------------------------------------------------------
__global__ __launch_bounds__(256) void prep_x(const float* __restrict__ x,
                                              u16* __restrict__ xh,
                                              u16* __restrict__ xt) {
  __shared__ float tile[64][65];
  const int f0 = blockIdx.x * 64, n0 = blockIdx.y * 64, b = blockIdx.z;
  const int t = threadIdx.x;
  const float* xb = x + (size_t)b * BS;
#pragma unroll
  for (int it = 0; it < 16; ++it) {
    int idx = it * 256 + t;
    int r = idx >> 6, c = idx & 63;
    float v = xb[(f0 + r) * 256 + n0 + c];
    tile[r][c] = v;
    xh[(size_t)b * BS + (f0 + r) * 256 + n0 + c] = f2bf(v);
  }
  __syncthreads();
#pragma unroll
  for (int it = 0; it < 16; ++it) {
    int idx = it * 256 + t;
    int rr = idx >> 6, cc = idx & 63;
    xt[(size_t)b * BS + (n0 + rr) * 256 + f0 + cc] = f2bf(tile[cc][rr]);
  }
}

// ---------------------------------------------------------------------------
// prep_w: Wh = bf16(W) (row-major [dd][512], k-contiguous); consts.
// grid 64, block 256.
// ---------------------------------------------------------------------------
__global__ __launch_bounds__(256) void prep_w(const float* __restrict__ W,
                                              const float* __restrict__ a,
                                              u16* __restrict__ Wh,
                                              float* __restrict__ c2m,
                                              float* __restrict__ sgn,
                                              float* __restrict__ a06) {
  const int t = threadIdx.x;
#pragma unroll
  for (int e = 0; e < 8; ++e) {
    int i = blockIdx.x * 2048 + e * 256 + t;
    Wh[i] = f2bf(W[i]);
  }
  if (blockIdx.x == 0) {
    float av = a[t];
    c2m[t] = fabsf(0.4f * av);
    sgn[t] = (av >= 0.f) ? 1.f : -1.f;
    a06[t] = 0.6f * av;
  }
}

// ---------------------------------------------------------------------------
// MFMA helpers: tile [128 rows][64 k] bf16 in LDS (16 KiB), rows = 128B.
// XOR swizzle chunk c^(r&7) applied on the *global source* (global_load_lds
// writes linearly) and identically on the frag read — rule #21.
// ---------------------------------------------------------------------------
__device__ __forceinline__ void stage_tile(const u16* __restrict__ g, int row0,
                                           int stride, int k0, u16* lds,
                                           int tid) {
#pragma unroll
  for (int it = 0; it < 4; ++it) {
    int slot = it * 256 + tid;
    int r = slot >> 3, c = slot & 7;
    int cs = c ^ (r & 7);
    const u16* src = g + (size_t)(row0 + r) * stride + k0 + cs * 8;
    u16* dst = lds + (size_t)(it * 256 + (tid & ~63)) * 8;  // wave-uniform base
    __builtin_amdgcn_global_load_lds((gv_t*)src, (lv_t*)dst, 16, 0, 0);
  }
}

__device__ __forceinline__ short8v frag(const u16* lds, int rb, int sk,
                                        int lane) {
  int r = rb * 16 + (lane & 15);
  int c = sk * 4 + (lane >> 4);
  int cs = c ^ (r & 7);
  return *(const short8v*)(lds + r * 64 + cs * 8);
}

// ---------------------------------------------------------------------------
// k1: dual projection GEMMs via MFMA bf16, 128x128 block tiles, K=256, BK=64.
// tiles 0-3: L2p[n][dd] = c2m[dd]*(xt·W1^T + b_lin[dd])  (A=xt rows n, B=W1)
// tiles 4-7: R2t[dd][n] = c2m[dd]*(W2·xt^T); SR[n] += 0.6a[dd]*R  (A=W2, B=xt)
// grid (8, 8b) = 64 blocks, 4 waves, wave tile 64x64 (4x4 16x16 frags).
// C layout (m89-verified): col = lane&15, row = (lane>>4)*4 + reg.
// ---------------------------------------------------------------------------
__global__ __launch_bounds__(256) void k1_mfma(
    const u16* __restrict__ xt, const u16* __restrict__ Wh,
    const float* __restrict__ b_lin, const float* __restrict__ c2m,
    const float* __restrict__ a06, float* __restrict__ L2p,
    float* __restrict__ R2t, float* __restrict__ SR) {
  __shared__ u16 At[128 * 64];
  __shared__ u16 Bt[128 * 64];
  const int tile = blockIdx.x, b = blockIdx.y;
  const bool isR = tile >= 4;
  const int t2 = tile & 3;
  const int mblk = (t2 >> 1) * 128, nblk = (t2 & 1) * 128;
  const int tid = threadIdx.x, lane = tid & 63, wid = tid >> 6;
  const int wr = (wid >> 1) * 64, wc = (wid & 1) * 64;

  const u16 *Ab, *Bb;
  int as_, bs_, ak;
  if (!isR) {
    Ab = xt + (size_t)b * BS; as_ = 256; ak = 0;   // A rows = n
    Bb = Wh; bs_ = 512;                            // B rows = dd (W1: f 0..255)
  } else {
    Ab = Wh; as_ = 512; ak = 256;                  // A rows = dd (W2: f 256..)
    Bb = xt + (size_t)b * BS; bs_ = 256;           // B rows = n
  }

  f32x4 acc[4][4];
#pragma unroll
  for (int i = 0; i < 4; ++i)
#pragma unroll
    for (int j = 0; j < 4; ++j) acc[i][j] = f32x4{0.f, 0.f, 0.f, 0.f};

  for (int ks = 0; ks < 4; ++ks) {
    stage_tile(Ab, mblk, as_, ak + ks * 64, At, tid);
    stage_tile(Bb, nblk, bs_, ks * 64, Bt, tid);
    __syncthreads();
#pragma unroll
    for (int sk = 0; sk < 2; ++sk) {
      short8v af[4], bf4[4];
#pragma unroll
      for (int i = 0; i < 4; ++i) af[i] = frag(At, (wr >> 4) + i, sk, lane);
#pragma unroll
      for (int j = 0; j < 4; ++j) bf4[j] = frag(Bt, (wc >> 4) + j, sk, lane);
#pragma unroll
      for (int i = 0; i < 4; ++i)
#pragma unroll
        for (int j = 0; j < 4; ++j)
          acc[i][j] = __builtin_amdgcn_mfma_f32_16x16x32_bf16(
              af[i], bf4[j], acc[i][j], 0, 0, 0);
    }
    __syncthreads();
  }

  if (!isR) {
#pragma unroll
    for (int cf = 0; cf < 4; ++cf) {
      int col = nblk + wc + cf * 16 + (lane & 15);
      float c2 = c2m[col], bl = b_lin[col];
#pragma unroll
      for (int rf = 0; rf < 4; ++rf) {
        int rbase = mblk + wr + rf * 16 + ((lane >> 4) << 2);
#pragma unroll
        for (int q = 0; q < 4; ++q)
          L2p[(size_t)b * BS + (size_t)(rbase + q) * 256 + col] =
              c2 * (acc[rf][cf][q] + bl);
      }
    }
  } else {
    float srp[4] = {0.f, 0.f, 0.f, 0.f};
#pragma unroll
    for (int rf = 0; rf < 4; ++rf) {
      int rbase = mblk + wr + rf * 16 + ((lane >> 4) << 2);
#pragma unroll
      for (int q = 0; q < 4; ++q) {
        int row = rbase + q;
        float c2 = c2m[row], w6 = a06[row];
#pragma unroll
        for (int cf = 0; cf < 4; ++cf) {
          float v = acc[rf][cf][q];
          R2t[(size_t)b * BS + (size_t)row * 256 + nblk + wc + cf * 16 +
              (lane & 15)] = c2 * v;
          srp[cf] = fmaf(w6, v, srp[cf]);
        }
      }
    }
#pragma unroll
    for (int cf = 0; cf < 4; ++cf) {
      float v = srp[cf];
      v += __shfl_xor(v, 16, 64);
      v += __shfl_xor(v, 32, 64);
      if ((lane >> 4) == 0)
        atomicAdd(&SR[b * 256 + nblk + wc + cf * 16 + lane], v);
    }
  }
}

// ---------------------------------------------------------------------------
// k2: e'[i,j] = SR[j] + bias + sum_d sgn[d]*|L2p[i,d] + R2t[d,j]|, mask,
// softmax over j; writes attn bf16 [i][j] (k-contiguous for k3 B-operand).
// grid (32 i-tiles, 8 b) = 256 blocks of 512 thr (8 waves/CU). thread =
// (j, ih); i-tile 8 = 2 halves of 4 rows. L rows packed float4 in LDS ->
// inner d-step: 1 uniform ds_read_b128 + 1 ds_read_b32 + 1 vmem + 8 VALU.
// ---------------------------------------------------------------------------
__global__ __launch_bounds__(512) void k2_scores(
    const float* __restrict__ R2t, const float* __restrict__ L2p,
    const float* __restrict__ sgn, const float* __restrict__ SR,
    const int* __restrict__ adj, const float* __restrict__ bias,
    u16* __restrict__ attnh) {
  __shared__ float4 Lq[2][256];
  __shared__ float sS[256];
  __shared__ float redm[8][4], reds[8][4];
  const int t = threadIdx.x, j = t & 255, ih = t >> 8;
  const int b = blockIdx.y, i0 = blockIdx.x * 8;
  {
    const float* Lb = L2p + (size_t)b * BS + (size_t)(i0 + ih * 4) * 256;
    Lq[ih][j] = make_float4(Lb[j], Lb[256 + j], Lb[512 + j], Lb[768 + j]);
    if (t < 256) sS[t] = sgn[t];
  }
  __syncthreads();

  const float* Rb = R2t + (size_t)b * BS;
  float e0 = 0.f, e1 = 0.f, e2 = 0.f, e3 = 0.f;
#pragma unroll 8
  for (int d = 0; d < 256; ++d) {
    float rv = Rb[d * 256 + j];
    float4 lq = Lq[ih][d];
    float sd = sS[d];
    float t0 = lq.x + rv, t1 = lq.y + rv, t2 = lq.z + rv, t3 = lq.w + rv;
    e0 = fmaf(sd, fabsf(t0), e0);
    e1 = fmaf(sd, fabsf(t1), e1);
    e2 = fmaf(sd, fabsf(t2), e2);
    e3 = fmaf(sd, fabsf(t3), e3);
  }
  float ev[4] = {e0, e1, e2, e3};
  const float srj = SR[b * 256 + j];
  const float NEG_INF = -__builtin_inff();
#pragma unroll
  for (int ii = 0; ii < 4; ++ii) {
    int row = i0 + ih * 4 + ii;
    ev[ii] += srj + bias[row * 256 + j];
    ev[ii] = (adj[(size_t)b * BS + (size_t)row * 256 + j] == 0) ? NEG_INF
                                                                : ev[ii];
  }
  const int wid = t >> 6, lane = t & 63, wb = ih * 4;
#pragma unroll
  for (int ii = 0; ii < 4; ++ii) {
    float v = ev[ii];
#pragma unroll
    for (int off = 32; off >= 1; off >>= 1) v = fmaxf(v, __shfl_xor(v, off, 64));
    if (lane == 0) redm[wid][ii] = v;
  }
  __syncthreads();
  float p4[4];
#pragma unroll
  for (int ii = 0; ii < 4; ++ii) {
    float m = fmaxf(fmaxf(redm[wb][ii], redm[wb + 1][ii]),
                    fmaxf(redm[wb + 2][ii], redm[wb + 3][ii]));
    p4[ii] = (m == NEG_INF) ? 1.f : __expf(ev[ii] - m);
  }
#pragma unroll
  for (int ii = 0; ii < 4; ++ii) {
    float v = p4[ii];
#pragma unroll
    for (int off = 32; off >= 1; off >>= 1) v += __shfl_xor(v, off, 64);
    if (lane == 0) reds[wid][ii] = v;
  }
  __syncthreads();
#pragma unroll
  for (int ii = 0; ii < 4; ++ii) {
    float ssum = reds[wb][ii] + reds[wb + 1][ii] + reds[wb + 2][ii] +
                 reds[wb + 3][ii];
    attnh[(size_t)b * BS + (size_t)(i0 + ih * 4 + ii) * 256 + j] =
        f2bf(p4[ii] / ssum);
  }
}

// ---------------------------------------------------------------------------
// k3: out[b][f][i] = sigmoid( sum_j xh[f][j]*attn[i][j] ) + x[b][f][i]
// MFMA: A = xh rows f, B = attn rows i (both k=j contiguous). 128x128 tiles,
// grid (4, 8b) = 32 blocks. Residual added in exact f32.
// ---------------------------------------------------------------------------
__global__ __launch_bounds__(256) void k3_mfma(const u16* __restrict__ xh,
                                               const u16* __restrict__ attnh,
                                               const float* __restrict__ x,
                                               float* __restrict__ out) {
  __shared__ u16 At[128 * 64];
  __shared__ u16 Bt[128 * 64];
  const int t2 = blockIdx.x, b = blockIdx.y;
  const int mblk = (t2 >> 1) * 128, nblk = (t2 & 1) * 128;
  const int tid = threadIdx.x, lane = tid & 63, wid = tid >> 6;
  const int wr = (wid >> 1) * 64, wc = (wid & 1) * 64;
  const u16* Ab = xh + (size_t)b * BS;
  const u16* Bb = attnh + (size_t)b * BS;

  f32x4 acc[4][4];
#pragma unroll
  for (int i = 0; i < 4; ++i)
#pragma unroll
    for (int j = 0; j < 4; ++j) acc[i][j] = f32x4{0.f, 0.f, 0.f, 0.f};

  for (int ks = 0; ks < 4; ++ks) {
    stage_tile(Ab, mblk, 256, ks * 64, At, tid);
    stage_tile(Bb, nblk, 256, ks * 64, Bt, tid);
    __syncthreads();
#pragma unroll
    for (int sk = 0; sk < 2; ++sk) {
      short8v af[4], bf4[4];
#pragma unroll
      for (int i = 0; i < 4; ++i) af[i] = frag(At, (wr >> 4) + i, sk, lane);
#pragma unroll
      for (int j = 0; j < 4; ++j) bf4[j] = frag(Bt, (wc >> 4) + j, sk, lane);
#pragma unroll
      for (int i = 0; i < 4; ++i)
#pragma unroll
        for (int j = 0; j < 4; ++j)
          acc[i][j] = __builtin_amdgcn_mfma_f32_16x16x32_bf16(
              af[i], bf4[j], acc[i][j], 0, 0, 0);
    }
    __syncthreads();
  }

#pragma unroll
  for (int cf = 0; cf < 4; ++cf) {
    int col = nblk + wc + cf * 16 + (lane & 15);
#pragma unroll
    for (int rf = 0; rf < 4; ++rf) {
      int rbase = mblk + wr + rf * 16 + ((lane >> 4) << 2);
#pragma unroll
      for (int q = 0; q < 4; ++q) {
        size_t idx = (size_t)b * BS + (size_t)(rbase + q) * 256 + col;
        float sg = 1.f / (1.f + __expf(-acc[rf][cf][q]));
        out[idx] = sg + x[idx];
      }
    }
  }
}

extern "C" void kernel_launch(void* const* d_in, const int* in_sizes, int n_in,
                              void* d_out, int out_size, void* d_ws,
                              size_t ws_size, hipStream_t stream) {
  const float* x = (const float*)d_in[0];
  const int* adj = (const int*)d_in[1];
  const float* W = (const float*)d_in[2];
  const float* b_lin = (const float*)d_in[3];
  const float* a = (const float*)d_in[4];
  const float* bias = (const float*)d_in[5];
  float* out = (float*)d_out;

  float* f = (float*)d_ws;
  float* L2p = f;                    // 524288
  float* R2t = L2p + BB * BS;        // 524288
  float* SR = R2t + BB * BS;         // 2048
  float* p = SR + BB * 256;
  u16* xh = (u16*)p;                 // 524288 u16 = 262144 f
  p += 262144;
  u16* xt = (u16*)p;                 // 262144 f
  p += 262144;
  u16* Wh = (u16*)p;                 // 131072 u16 = 65536 f
  p += 65536;
  u16* attnh = (u16*)p;              // 262144 f
  p += 262144;
  float* c2m = p;                    // 256
  float* sgn = c2m + 256;            // 256
  float* a06 = sgn + 256;            // 256

  hipMemsetAsync(SR, 0, BB * 256 * sizeof(float), stream);
  prep_x<<<dim3(4, 4, BB), 256, 0, stream>>>(x, xh, xt);
  prep_w<<<64, 256, 0, stream>>>(W, a, Wh, c2m, sgn, a06);
  k1_mfma<<<dim3(8, BB), 256, 0, stream>>>(xt, Wh, b_lin, c2m, a06, L2p, R2t,
                                           SR);
  k2_scores<<<dim3(32, BB), 512, 0, stream>>>(R2t, L2p, sgn, SR, adj, bias,
                                              attnh);
  k3_mfma<<<dim3(4, BB), 256, 0, stream>>>(xh, attnh, x, out);
}

// Round 4
// 45.114 us; speedup vs baseline: 2.0439x; 1.1220x over previous
//
#include <hip/hip_runtime.h>
#include <hip/hip_bf16.h>
#include <math.h>

#define BB 8
#define BS 65536  // 256*256

typedef __attribute__((ext_vector_type(8))) short short8v;
typedef __attribute__((ext_vector_type(4))) float f32x4;
typedef unsigned short u16;
typedef __attribute__((address_space(1))) const void gv_t;
typedef __attribute__((address_space(3))) void lv_t;

__device__ __forceinline__ u16 f2bf(float v) {
  __hip_bfloat16 h = __float2bfloat16(v);
  return *reinterpret_cast<u16*>(&h);
}

// ---------------------------------------------------------------------------
// prep: one kernel, 137 blocks x 256 thr.
//  blocks 0..127  : xt[b][n][f] = bf16(x[b][f][n])  (LDS-tiled transpose)
//  blocks 128..135: Wh = bf16(W)  row-major [dd][512] (k-contiguous)
//  block  136     : c2m[d] = |0.4 a[d]|, sgn[d] = sign(a[d])
// ---------------------------------------------------------------------------
__global__ __launch_bounds__(256) void prep(const float* __restrict__ x,
                                            const float* __restrict__ W,
                                            const float* __restrict__ a,
                                            u16* __restrict__ xt,
                                            u16* __restrict__ Wh,
                                            float* __restrict__ c2m,
                                            float* __restrict__ sgn) {
  const int bk = blockIdx.x, t = threadIdx.x;
  if (bk < 128) {
    __shared__ float tile[64][65];
    const int b = bk >> 4, t2 = bk & 15;
    const int f0 = (t2 & 3) * 64, n0 = (t2 >> 2) * 64;
    const float* xb = x + (size_t)b * BS;
#pragma unroll
    for (int it = 0; it < 16; ++it) {
      int idx = it * 256 + t;
      int r = idx >> 6, c = idx & 63;
      tile[r][c] = xb[(f0 + r) * 256 + n0 + c];
    }
    __syncthreads();
#pragma unroll
    for (int it = 0; it < 16; ++it) {
      int idx = it * 256 + t;
      int rr = idx >> 6, cc = idx & 63;
      xt[(size_t)b * BS + (n0 + rr) * 256 + f0 + cc] = f2bf(tile[cc][rr]);
    }
  } else if (bk < 136) {
    const int base = (bk - 128) * 16384;
#pragma unroll
    for (int it = 0; it < 16; ++it) {
      int i = base + (it * 256 + t) * 4;
      float4 v = *(const float4*)(W + i);
      u16 o[4] = {f2bf(v.x), f2bf(v.y), f2bf(v.z), f2bf(v.w)};
      *(uint2*)(Wh + i) = *(const uint2*)o;
    }
  } else {
    float av = a[t];
    c2m[t] = fabsf(0.4f * av);
    sgn[t] = (av >= 0.f) ? 1.f : -1.f;
  }
}

// ---------------------------------------------------------------------------
// LDS tile [64 rows][64 k] bf16 (8 KiB), row = 128 B = 8 chunks of 16 B.
// XOR swizzle chunk cs = c ^ (r&7); gload_lds writes linearly so the swizzle
// is applied on the GLOBAL SOURCE address + identically on frag read (#21).
// ---------------------------------------------------------------------------
__device__ __forceinline__ void stage_tile(const u16* __restrict__ g, int row0,
                                           int stride, int k0, u16* lds,
                                           int tid) {
#pragma unroll
  for (int it = 0; it < 2; ++it) {
    int slot = it * 256 + tid;
    int r = slot >> 3, c = slot & 7;
    int cs = c ^ (r & 7);
    const u16* src = g + (size_t)(row0 + r) * stride + k0 + cs * 8;
    u16* dst = lds + (size_t)(it * 256 + (tid & ~63)) * 8;
    __builtin_amdgcn_global_load_lds((gv_t*)src, (lv_t*)dst, 16, 0, 0);
  }
}

__device__ __forceinline__ short8v frag(const u16* lds, int rb, int sk,
                                        int lane) {
  int r = rb * 16 + (lane & 15);
  int c = sk * 4 + (lane >> 4);
  int cs = c ^ (r & 7);
  return *(const short8v*)(lds + r * 64 + cs * 8);
}

// ---------------------------------------------------------------------------
// k1: dual projection GEMMs, 64x64 block tiles, K=256, BK=64, 4 waves,
// wave-tile 32x32 (2x2 16x16x32 frags). grid (32, 8b) = 256 blocks.
//  tiles 0..15 : L2p[n][dd] = c2m[dd]*(xt·W1^T + b_lin[dd])
//  tiles 16..31: R2t[dd][n] = c2m[dd]*(W2·xt^T)
// C layout: col = lane&15, row = (lane>>4)*4 + q.
// ---------------------------------------------------------------------------
__global__ __launch_bounds__(256) void k1_mfma(
    const u16* __restrict__ xt, const u16* __restrict__ Wh,
    const float* __restrict__ b_lin, const float* __restrict__ c2m,
    float* __restrict__ L2p, float* __restrict__ R2t) {
  __shared__ u16 At[64 * 64];
  __shared__ u16 Bt[64 * 64];
  const int tile = blockIdx.x, b = blockIdx.y;
  const bool isR = tile >= 16;
  const int t2 = tile & 15;
  const int mblk = (t2 >> 2) * 64, nblk = (t2 & 3) * 64;
  const int tid = threadIdx.x, lane = tid & 63, wid = tid >> 6;
  const int wr = (wid >> 1) * 32, wc = (wid & 1) * 32;

  const u16 *Ab, *Bb;
  int as_, bs_, ak;
  if (!isR) {
    Ab = xt + (size_t)b * BS; as_ = 256; ak = 0;  // A rows = n, k = f
    Bb = Wh; bs_ = 512;                           // B rows = dd (W1)
  } else {
    Ab = Wh; as_ = 512; ak = 256;                 // A rows = dd (W2)
    Bb = xt + (size_t)b * BS; bs_ = 256;          // B rows = n
  }

  f32x4 acc[2][2];
#pragma unroll
  for (int i = 0; i < 2; ++i)
#pragma unroll
    for (int j = 0; j < 2; ++j) acc[i][j] = f32x4{0.f, 0.f, 0.f, 0.f};

  for (int ks = 0; ks < 4; ++ks) {
    stage_tile(Ab, mblk, as_, ak + ks * 64, At, tid);
    stage_tile(Bb, nblk, bs_, ks * 64, Bt, tid);
    __syncthreads();
#pragma unroll
    for (int sk = 0; sk < 2; ++sk) {
      short8v af[2], bf2[2];
#pragma unroll
      for (int i = 0; i < 2; ++i) af[i] = frag(At, (wr >> 4) + i, sk, lane);
#pragma unroll
      for (int j = 0; j < 2; ++j) bf2[j] = frag(Bt, (wc >> 4) + j, sk, lane);
#pragma unroll
      for (int i = 0; i < 2; ++i)
#pragma unroll
        for (int j = 0; j < 2; ++j)
          acc[i][j] = __builtin_amdgcn_mfma_f32_16x16x32_bf16(
              af[i], bf2[j], acc[i][j], 0, 0, 0);
    }
    __syncthreads();
  }

  if (!isR) {
#pragma unroll
    for (int cf = 0; cf < 2; ++cf) {
      int col = nblk + wc + cf * 16 + (lane & 15);
      float c2 = c2m[col], bl = b_lin[col];
#pragma unroll
      for (int rf = 0; rf < 2; ++rf) {
        int rbase = mblk + wr + rf * 16 + ((lane >> 4) << 2);
#pragma unroll
        for (int q = 0; q < 4; ++q)
          L2p[(size_t)b * BS + (size_t)(rbase + q) * 256 + col] =
              c2 * (acc[rf][cf][q] + bl);
      }
    }
  } else {
#pragma unroll
    for (int rf = 0; rf < 2; ++rf) {
      int rbase = mblk + wr + rf * 16 + ((lane >> 4) << 2);
#pragma unroll
      for (int q = 0; q < 4; ++q) {
        int row = rbase + q;
        float c2 = c2m[row];
#pragma unroll
        for (int cf = 0; cf < 2; ++cf)
          R2t[(size_t)b * BS + (size_t)row * 256 + nblk + wc + cf * 16 +
              (lane & 15)] = c2 * acc[rf][cf][q];
      }
    }
  }
}

// ---------------------------------------------------------------------------
// k2: e[i,j] = 1.5*sum_d sgn[d]*R2t[d,j]  (separable right term, free ride on
//              the same R2t stream) + bias[i,j] + sum_d sgn[d]*|L2p[i,d]+R2t[d,j]|
// mask + softmax over j -> attn bf16 [i][j] (k-contiguous for k3).
// grid (32 i-tiles, 8 b) = 256 blocks x 512 thr; thread = (j, ih), i-tile 8.
// ---------------------------------------------------------------------------
__global__ __launch_bounds__(512) void k2_scores(
    const float* __restrict__ R2t, const float* __restrict__ L2p,
    const float* __restrict__ sgn, const int* __restrict__ adj,
    const float* __restrict__ bias, u16* __restrict__ attnh) {
  __shared__ float4 Lq[2][256];
  __shared__ float sS[256];
  __shared__ float redm[8][4], reds[8][4];
  const int t = threadIdx.x, j = t & 255, ih = t >> 8;
  const int b = blockIdx.y, i0 = blockIdx.x * 8;
  {
    const float* Lb = L2p + (size_t)b * BS + (size_t)(i0 + ih * 4) * 256;
    Lq[ih][j] = make_float4(Lb[j], Lb[256 + j], Lb[512 + j], Lb[768 + j]);
    if (t < 256) sS[t] = sgn[t];
  }
  __syncthreads();

  const float* Rb = R2t + (size_t)b * BS;
  float e0 = 0.f, e1 = 0.f, e2 = 0.f, e3 = 0.f, srj = 0.f;
#pragma unroll 16
  for (int d = 0; d < 256; ++d) {
    float rv = Rb[d * 256 + j];
    float4 lq = Lq[ih][d];
    float sd = sS[d];
    srj = fmaf(sd, rv, srj);
    float t0 = lq.x + rv, t1 = lq.y + rv, t2 = lq.z + rv, t3 = lq.w + rv;
    e0 = fmaf(sd, fabsf(t0), e0);
    e1 = fmaf(sd, fabsf(t1), e1);
    e2 = fmaf(sd, fabsf(t2), e2);
    e3 = fmaf(sd, fabsf(t3), e3);
  }
  float ev[4] = {e0, e1, e2, e3};
  const float sbase = 1.5f * srj;
  const float NEG_INF = -__builtin_inff();
#pragma unroll
  for (int ii = 0; ii < 4; ++ii) {
    int row = i0 + ih * 4 + ii;
    ev[ii] += sbase + bias[row * 256 + j];
    ev[ii] = (adj[(size_t)b * BS + (size_t)row * 256 + j] == 0) ? NEG_INF
                                                                : ev[ii];
  }
  const int wid = t >> 6, lane = t & 63, wb = ih * 4;
#pragma unroll
  for (int ii = 0; ii < 4; ++ii) {
    float v = ev[ii];
#pragma unroll
    for (int off = 32; off >= 1; off >>= 1) v = fmaxf(v, __shfl_xor(v, off, 64));
    if (lane == 0) redm[wid][ii] = v;
  }
  __syncthreads();
  float p4[4];
#pragma unroll
  for (int ii = 0; ii < 4; ++ii) {
    float m = fmaxf(fmaxf(redm[wb][ii], redm[wb + 1][ii]),
                    fmaxf(redm[wb + 2][ii], redm[wb + 3][ii]));
    p4[ii] = (m == NEG_INF) ? 1.f : __expf(ev[ii] - m);
  }
#pragma unroll
  for (int ii = 0; ii < 4; ++ii) {
    float v = p4[ii];
#pragma unroll
    for (int off = 32; off >= 1; off >>= 1) v += __shfl_xor(v, off, 64);
    if (lane == 0) reds[wid][ii] = v;
  }
  __syncthreads();
#pragma unroll
  for (int ii = 0; ii < 4; ++ii) {
    float ssum = reds[wb][ii] + reds[wb + 1][ii] + reds[wb + 2][ii] +
                 reds[wb + 3][ii];
    attnh[(size_t)b * BS + (size_t)(i0 + ih * 4 + ii) * 256 + j] =
        f2bf(p4[ii] / ssum);
  }
}

// ---------------------------------------------------------------------------
// k3: out[b][f][i] = sigmoid( sum_j x[f][j]*attn[i][j] ) + x[b][f][i]
// 64x64 tiles, grid (16, 8b) = 128 blocks. A = x (f32, reg-staged -> bf16,
// swizzle applied on the LDS-WRITE side); B = attnh via gload_lds.
// ---------------------------------------------------------------------------
__global__ __launch_bounds__(256) void k3_mfma(const u16* __restrict__ attnh,
                                               const float* __restrict__ x,
                                               float* __restrict__ out) {
  __shared__ u16 At[64 * 64];
  __shared__ u16 Bt[64 * 64];
  const int t2 = blockIdx.x, b = blockIdx.y;
  const int mblk = (t2 >> 2) * 64, nblk = (t2 & 3) * 64;
  const int tid = threadIdx.x, lane = tid & 63, wid = tid >> 6;
  const int wr = (wid >> 1) * 32, wc = (wid & 1) * 32;
  const float* Ax = x + (size_t)b * BS;
  const u16* Bb = attnh + (size_t)b * BS;

  f32x4 acc[2][2];
#pragma unroll
  for (int i = 0; i < 2; ++i)
#pragma unroll
    for (int j = 0; j < 2; ++j) acc[i][j] = f32x4{0.f, 0.f, 0.f, 0.f};

  for (int ks = 0; ks < 4; ++ks) {
    // B: attn bf16 via async gload_lds (source pre-swizzled)
    stage_tile(Bb, nblk, 256, ks * 64, Bt, tid);
    // A: x f32 -> bf16 reg-staged; swizzle on the ds-write address
#pragma unroll
    for (int it = 0; it < 2; ++it) {
      int slot = it * 256 + tid;
      int r = slot >> 3, c = slot & 7;
      const float* src = Ax + (size_t)(mblk + r) * 256 + ks * 64 + c * 8;
      float4 v0 = *(const float4*)src;
      float4 v1 = *(const float4*)(src + 4);
      u16 o[8] = {f2bf(v0.x), f2bf(v0.y), f2bf(v0.z), f2bf(v0.w),
                  f2bf(v1.x), f2bf(v1.y), f2bf(v1.z), f2bf(v1.w)};
      int cs = c ^ (r & 7);
      *(short8v*)(At + r * 64 + cs * 8) = *(const short8v*)o;
    }
    __syncthreads();
#pragma unroll
    for (int sk = 0; sk < 2; ++sk) {
      short8v af[2], bf2[2];
#pragma unroll
      for (int i = 0; i < 2; ++i) af[i] = frag(At, (wr >> 4) + i, sk, lane);
#pragma unroll
      for (int j = 0; j < 2; ++j) bf2[j] = frag(Bt, (wc >> 4) + j, sk, lane);
#pragma unroll
      for (int i = 0; i < 2; ++i)
#pragma unroll
        for (int j = 0; j < 2; ++j)
          acc[i][j] = __builtin_amdgcn_mfma_f32_16x16x32_bf16(
              af[i], bf2[j], acc[i][j], 0, 0, 0);
    }
    __syncthreads();
  }

#pragma unroll
  for (int cf = 0; cf < 2; ++cf) {
    int col = nblk + wc + cf * 16 + (lane & 15);
#pragma unroll
    for (int rf = 0; rf < 2; ++rf) {
      int rbase = mblk + wr + rf * 16 + ((lane >> 4) << 2);
#pragma unroll
      for (int q = 0; q < 4; ++q) {
        size_t idx = (size_t)b * BS + (size_t)(rbase + q) * 256 + col;
        float sg = 1.f / (1.f + __expf(-acc[rf][cf][q]));
        out[idx] = sg + x[idx];
      }
    }
  }
}

extern "C" void kernel_launch(void* const* d_in, const int* in_sizes, int n_in,
                              void* d_out, int out_size, void* d_ws,
                              size_t ws_size, hipStream_t stream) {
  const float* x = (const float*)d_in[0];
  const int* adj = (const int*)d_in[1];
  const float* W = (const float*)d_in[2];
  const float* b_lin = (const float*)d_in[3];
  const float* a = (const float*)d_in[4];
  const float* bias = (const float*)d_in[5];
  float* out = (float*)d_out;

  float* f = (float*)d_ws;
  float* L2p = f;                  // 524288 f
  float* R2t = L2p + BB * BS;      // 524288 f
  float* p = R2t + BB * BS;
  u16* xt = (u16*)p;               // 524288 u16
  p += 262144;
  u16* Wh = (u16*)p;               // 131072 u16
  p += 65536;
  u16* attnh = (u16*)p;            // 524288 u16
  p += 262144;
  float* c2m = p;                  // 256
  float* sgn = c2m + 256;          // 256

  prep<<<137, 256, 0, stream>>>(x, W, a, xt, Wh, c2m, sgn);
  k1_mfma<<<dim3(32, BB), 256, 0, stream>>>(xt, Wh, b_lin, c2m, L2p, R2t);
  k2_scores<<<dim3(32, BB), 512, 0, stream>>>(R2t, L2p, sgn, adj, bias, attnh);
  k3_mfma<<<dim3(16, BB), 256, 0, stream>>>(attnh, x, out);
}